// Round 1
// 323.567 us; speedup vs baseline: 1.1593x; 1.1593x over previous
//
#include <hip/hip_runtime.h>

#define C 64
#define EPS 1e-5f

typedef __attribute__((ext_vector_type(8))) short bf16x8;
typedef __attribute__((ext_vector_type(4))) float f32x4;

// ---- bf16 pack/unpack helpers (RNE) ---------------------------------------
static __device__ __forceinline__ unsigned int f2bf(float f) {
  unsigned int x = __float_as_uint(f);
  return (x + 0x7fffu + ((x >> 16) & 1u)) >> 16;
}
static __device__ __forceinline__ float bflo2f(unsigned int p) {  // low ushort
  return __uint_as_float(p << 16);
}
static __device__ __forceinline__ float bfhi2f(unsigned int p) {  // high ushort
  return __uint_as_float(p & 0xffff0000u);
}

// ---------------------------------------------------------------------------
// Prep: w1T[kout][c] = bf16(w1[c][kout])   (128 x 64)
//       w2T[cout][k] = bf16(w2[k][cout])   (64 x 128)
// Transposed so MFMA B-fragments (8 contiguous K-dim elems per lane) are
// contiguous rows in LDS.
// ---------------------------------------------------------------------------
__global__ __launch_bounds__(256) void prep_weights(
    const float* __restrict__ w1, const float* __restrict__ w2,
    unsigned short* __restrict__ w1T, unsigned short* __restrict__ w2T) {
  int idx = blockIdx.x * 256 + threadIdx.x;
  if (idx < 2 * C * C) {
    int k = idx >> 6, c = idx & 63;
    w1T[idx] = (unsigned short)f2bf(w1[c * 2 * C + k]);
  } else if (idx < 4 * C * C) {
    int j = idx - 2 * C * C;
    int c = j >> 7, k = j & 127;
    w2T[j] = (unsigned short)f2bf(w2[k * C + c]);
  }
}

// ---------------------------------------------------------------------------
// Fused node kernel: LN -> GEMM1(bf16 MFMA) -> silu -> GEMM2 -> *vln -> D16.
// Block = 256 threads (4 waves), 64 nodes/block; wave w owns rows 16w..16w+15.
// LDS pitches chosen so pitch%32dw == 4 -> ds_read_b128 at the bank floor.
// ---------------------------------------------------------------------------
__global__ __launch_bounds__(256, 2) void node_kernel(
    const float* __restrict__ x, const float* __restrict__ vec,
    const float* __restrict__ ln_scale, const float* __restrict__ ln_bias,
    const float* __restrict__ vln_w,
    const unsigned short* __restrict__ w1T, const float* __restrict__ b1,
    const unsigned short* __restrict__ w2T, const float* __restrict__ b2,
    uint2* __restrict__ D16, int n_nodes) {
  __shared__ unsigned short An[64 * 72];    // x_norm bf16 [row][c], pitch 72
  __shared__ unsigned short Ss[64 * 136];   // silu(h) bf16 [row][k], pitch 136
  __shared__ unsigned short W1s[128 * 72];  // w1T [kout][c], pitch 72
  __shared__ unsigned short W2s[64 * 136];  // w2T [cout][k], pitch 136

  const int t = threadIdx.x;
  const int lane = t & 63;
  const int wave = t >> 6;
  const int l15 = lane & 15;
  const int q = lane >> 4;

  // ---- stage weights (coalesced uint4 copies) ----
  {
    int r1 = t >> 1, h2 = t & 1;  // W1: 128 rows x 2 halves of 32 ushorts
    const uint4* s1 = (const uint4*)(w1T + r1 * 64 + h2 * 32);
    uint4* d1 = (uint4*)(W1s + r1 * 72 + h2 * 32);
    d1[0] = s1[0]; d1[1] = s1[1]; d1[2] = s1[2]; d1[3] = s1[3];
    int r2 = t >> 2, qd = t & 3;  // W2: 64 rows x 4 quarters of 32 ushorts
    const uint4* s2 = (const uint4*)(w2T + r2 * 128 + qd * 32);
    uint4* d2 = (uint4*)(W2s + r2 * 136 + qd * 32);
    d2[0] = s2[0]; d2[1] = s2[1]; d2[2] = s2[2]; d2[3] = s2[3];
  }

  // ---- LayerNorm: 4 threads per row, 16 channels each ----
  {
    int rowl = t >> 2;  // 0..63
    int part = t & 3;
    int node = blockIdx.x * 64 + rowl;
    int nc = node < n_nodes ? node : n_nodes - 1;  // clamp: keeps loads legal
    const float* xp = x + (size_t)nc * C + part * 16;
    float xv[16];
    float s = 0.f;
#pragma unroll
    for (int i = 0; i < 4; i++) {
      float4 v = *(const float4*)(xp + i * 4);
      xv[i * 4 + 0] = v.x; xv[i * 4 + 1] = v.y;
      xv[i * 4 + 2] = v.z; xv[i * 4 + 3] = v.w;
      s += v.x + v.y + v.z + v.w;
    }
    s += __shfl_xor(s, 1);
    s += __shfl_xor(s, 2);
    float mean = s * (1.f / C);
    float vs = 0.f;
#pragma unroll
    for (int i = 0; i < 16; i++) {
      float d = xv[i] - mean;
      vs += d * d;
    }
    vs += __shfl_xor(vs, 1);
    vs += __shfl_xor(vs, 2);
    float rs = rsqrtf(vs * (1.f / C) + EPS);
    float ls[16], lb[16];
#pragma unroll
    for (int i = 0; i < 4; i++) {
      float4 a = *(const float4*)(ln_scale + part * 16 + i * 4);
      float4 b = *(const float4*)(ln_bias + part * 16 + i * 4);
      ls[i * 4 + 0] = a.x; ls[i * 4 + 1] = a.y; ls[i * 4 + 2] = a.z; ls[i * 4 + 3] = a.w;
      lb[i * 4 + 0] = b.x; lb[i * 4 + 1] = b.y; lb[i * 4 + 2] = b.z; lb[i * 4 + 3] = b.w;
    }
    unsigned int bp[8];
#pragma unroll
    for (int i = 0; i < 8; i++) {
      float e0 = (xv[2 * i] - mean) * rs * ls[2 * i] + lb[2 * i];
      float e1 = (xv[2 * i + 1] - mean) * rs * ls[2 * i + 1] + lb[2 * i + 1];
      bp[i] = f2bf(e0) | (f2bf(e1) << 16);
    }
    uint4* dst = (uint4*)(An + rowl * 72 + part * 16);
    uint4 p0 = {bp[0], bp[1], bp[2], bp[3]};
    uint4 p1 = {bp[4], bp[5], bp[6], bp[7]};
    dst[0] = p0;
    dst[1] = p1;
  }
  __syncthreads();

  const int Mbase = wave * 16;

  // ---- GEMM1: h = x_norm @ w1  (M=16/wave, N=128, K=64) ----
  // A-frag: lane holds A[l15][q*8+i]; B-frag: lane holds B[q*8+i][l15].
  bf16x8 a0 = *(const bf16x8*)(An + (Mbase + l15) * 72 + q * 8);
  bf16x8 a1 = *(const bf16x8*)(An + (Mbase + l15) * 72 + 32 + q * 8);
  f32x4 acc1[8];
#pragma unroll
  for (int nt = 0; nt < 8; nt++) {
    const unsigned short* wb = W1s + (nt * 16 + l15) * 72 + q * 8;
    bf16x8 b0 = *(const bf16x8*)(wb);
    bf16x8 b1f = *(const bf16x8*)(wb + 32);
    f32x4 z = {0.f, 0.f, 0.f, 0.f};
    z = __builtin_amdgcn_mfma_f32_16x16x32_bf16(a0, b0, z, 0, 0, 0);
    z = __builtin_amdgcn_mfma_f32_16x16x32_bf16(a1, b1f, z, 0, 0, 0);
    acc1[nt] = z;
  }
  // bias + silu (fp32) -> bf16 -> LDS.  D-layout: row = q*4+r, col = nt*16+l15.
#pragma unroll
  for (int nt = 0; nt < 8; nt++) {
    float bb = b1[nt * 16 + l15];
#pragma unroll
    for (int r = 0; r < 4; r++) {
      float h = acc1[nt][r] + bb;
      float sg = h / (1.f + __expf(-h));
      Ss[(Mbase + q * 4 + r) * 136 + nt * 16 + l15] = (unsigned short)f2bf(sg);
    }
  }
  __syncthreads();

  // ---- GEMM2: p = s @ w2  (M=16/wave, N=64, K=128) ----
  bf16x8 a2[4];
#pragma unroll
  for (int kt = 0; kt < 4; kt++)
    a2[kt] = *(const bf16x8*)(Ss + (Mbase + l15) * 136 + kt * 32 + q * 8);
  f32x4 acc2[4];
#pragma unroll
  for (int nt = 0; nt < 4; nt++) {
    f32x4 z = {0.f, 0.f, 0.f, 0.f};
#pragma unroll
    for (int kt = 0; kt < 4; kt++) {
      bf16x8 b = *(const bf16x8*)(W2s + (nt * 16 + l15) * 136 + kt * 32 + q * 8);
      z = __builtin_amdgcn_mfma_f32_16x16x32_bf16(a2[kt], b, z, 0, 0, 0);
    }
    acc2[nt] = z;
  }

  // ---- epilogue: p*vln_w, D = q*vec packed bf16 uint2 ----
#pragma unroll
  for (int nt = 0; nt < 4; nt++) {
    int cc = nt * 16 + l15;
    float bb = b2[cc];
    float vw = vln_w[cc];
#pragma unroll
    for (int r = 0; r < 4; r++) {
      int rl = Mbase + q * 4 + r;
      int nn = blockIdx.x * 64 + rl;
      if (nn < n_nodes) {
        float p = (acc2[nt][r] + bb) * vw;
        const float* vp = vec + (size_t)nn * (3 * C) + cc;
        float v0 = vp[0], v1 = vp[C], v2 = vp[2 * C];
        uint2 u;
        u.x = f2bf(p * v0) | (f2bf(p * v1) << 16);
        u.y = f2bf(p * v2);
        D16[(size_t)nn * C + cc] = u;
      }
    }
  }
}

// ---------------------------------------------------------------------------
// Per-edge: wave handles 4 edges, lane = channel. One dwordx2 gather per
// node-row (all 3 components packed bf16). M + indices via scalar loads.
// (unchanged this round)
// ---------------------------------------------------------------------------
__global__ __launch_bounds__(256) void edge_kernel(
    const int* __restrict__ senders, const int* __restrict__ receivers,
    const float* __restrict__ Mmat, const uint2* __restrict__ D2,
    float* __restrict__ dx, int n_edges) {
  int wid = threadIdx.x >> 6;
  int lane = threadIdx.x & 63;
  int e0 = (blockIdx.x * 4 + wid) * 4;
  if (e0 >= n_edges) return;
  e0 = __builtin_amdgcn_readfirstlane(e0);
  int nvalid = n_edges - e0;  // >=1; usually >=4

  int r[4], s[4];
#pragma unroll
  for (int j = 0; j < 4; j++) {
    int e = (j < nvalid) ? e0 + j : e0;  // clamp: keeps loads in-bounds
    r[j] = receivers[e];
    s[j] = senders[e];
  }
  uint2 dsv[4], drv[4];
#pragma unroll
  for (int j = 0; j < 4; j++) {
    dsv[j] = D2[(size_t)s[j] * C + lane];
    drv[j] = D2[(size_t)r[j] * C + lane];
  }
#pragma unroll
  for (int j = 0; j < 4; j++) {
    if (j < nvalid) {
      const float* M = Mmat + (size_t)(e0 + j) * 9;  // uniform -> s_load
      float m00 = M[0], m01 = M[1], m02 = M[2];
      float m10 = M[3], m11 = M[4], m12 = M[5];
      float m20 = M[6], m21 = M[7], m22 = M[8];
      float s0 = bflo2f(dsv[j].x), s1 = bfhi2f(dsv[j].x), s2 = bflo2f(dsv[j].y);
      float r0 = bflo2f(drv[j].x), r1 = bfhi2f(drv[j].x), r2 = bflo2f(drv[j].y);
      float f0 = m00 * s0 + m01 * s1 + m02 * s2;
      float f1 = m10 * s0 + m11 * s1 + m12 * s2;
      float f2 = m20 * s0 + m21 * s1 + m22 * s2;
      float dE = r0 * f0 + r1 * f1 + r2 * f2;
      atomicAdd(dx + (size_t)r[j] * C + lane, dE);
    }
  }
}

// ---------------------------------------------------------------------------
extern "C" void kernel_launch(void* const* d_in, const int* in_sizes, int n_in,
                              void* d_out, int out_size, void* d_ws, size_t ws_size,
                              hipStream_t stream) {
  const float* x        = (const float*)d_in[0];
  const float* vec      = (const float*)d_in[1];
  const int*   senders  = (const int*)d_in[2];
  const int*   receivers= (const int*)d_in[3];
  const float* Mmat     = (const float*)d_in[4];
  const float* ln_scale = (const float*)d_in[5];
  const float* ln_bias  = (const float*)d_in[6];
  const float* vln_w    = (const float*)d_in[7];
  const float* w1       = (const float*)d_in[8];
  const float* b1       = (const float*)d_in[9];
  const float* w2       = (const float*)d_in[10];
  const float* b2       = (const float*)d_in[11];
  float* dx = (float*)d_out;

  int n_nodes = in_sizes[0] / C;   // 50000
  int n_edges = in_sizes[2];       // 800000

  // Workspace: w1T (16KB bf16), w2T (16KB bf16), then D16 [N][C] uint2 (25.6 MB)
  unsigned short* w1T = (unsigned short*)d_ws;
  unsigned short* w2T = w1T + 2 * C * C;
  uint2* D16 = (uint2*)((char*)d_ws + 32768);

  prep_weights<<<64, 256, 0, stream>>>(w1, w2, w1T, w2T);

  node_kernel<<<(n_nodes + 63) / 64, 256, 0, stream>>>(
      x, vec, ln_scale, ln_bias, vln_w, w1T, b1, w2T, b2, D16, n_nodes);

  hipMemsetAsync(d_out, 0, (size_t)out_size * sizeof(float), stream);

  edge_kernel<<<(n_edges + 15) / 16, 256, 0, stream>>>(
      senders, receivers, Mmat, D16, dx, n_edges);
}